// Round 12
// baseline (231.359 us; speedup 1.0000x reference)
//
#include <hip/hip_runtime.h>
#include <math.h>

#define N_NODES 2048
#define N_EDGES 65536
#define SEQL 5
#define IN_F 32
#define HID 64
#define OUT_F 16
#define LN_EPS 1e-5f

// ================= k_deg_wcomb: 258 blocks x 256 =================
__global__ __launch_bounds__(256) void k_deg_wcomb(
        const int* __restrict__ ei, const float* __restrict__ ew,
        const float* __restrict__ Wcz, const float* __restrict__ Wlz,
        const float* __restrict__ bcz, const float* __restrict__ blz,
        const float* __restrict__ Wch, const float* __restrict__ Wlh,
        const float* __restrict__ bch, const float* __restrict__ blh,
        float* __restrict__ deg, int* __restrict__ cnt,
        float* __restrict__ Wzp, float* __restrict__ Whp, float* __restrict__ bUV){
    int b = blockIdx.x, t = threadIdx.x;
    if (b < 256){
        int e = b * 256 + t;
        int d = ei[N_EDGES + e];
        atomicAdd(&deg[d], ew[e]);
        atomicAdd(&cnt[d], 1);
    } else {
        const float* Wc = (b == 256) ? Wcz : Wch;
        const float* Wl = (b == 256) ? Wlz : Wlh;
        const float* bc = (b == 256) ? bcz : bch;
        const float* bl = (b == 256) ? blz : blh;
        float* Wp = (b == 256) ? Wzp : Whp;
        for (int idx = t; idx < IN_F*HID; idx += 256){
            int i = idx >> 6, f = idx & 63;
            float s = 0.f;
            #pragma unroll 8
            for (int k = 0; k < HID; ++k) s += Wc[i*HID+k] * Wl[k*HID+f];
            Wp[idx] = s;
        }
        if (t < HID){
            float s = bl[t];
            for (int k = 0; k < HID; ++k) s += bc[k] * Wl[k*HID+t];
            bUV[(b-256)*HID + t] = s;
        }
    }
}

// ================= k_scan: 1 block x 1024 =================
__global__ __launch_bounds__(1024) void k_scan(
        const float* __restrict__ deg, const int* __restrict__ cnt,
        int* __restrict__ rowptr, float* __restrict__ dinv, float* __restrict__ dself,
        int* __restrict__ fill){
    __shared__ int sc[1024];
    int t = threadIdx.x;
    int c0 = cnt[2*t], c1 = cnt[2*t+1];
    int ts = c0 + c1;
    sc[t] = ts;
    __syncthreads();
    for (int off = 1; off < 1024; off <<= 1){
        int v = (t >= off) ? sc[t - off] : 0;
        __syncthreads();
        sc[t] += v;
        __syncthreads();
    }
    int exc = sc[t] - ts;
    rowptr[2*t]   = exc;
    rowptr[2*t+1] = exc + c0;
    if (t == 1023) rowptr[N_NODES] = sc[t];
    float i0 = 1.f / sqrtf(deg[2*t] + 1.f);
    float i1 = 1.f / sqrtf(deg[2*t+1] + 1.f);
    dinv[2*t] = i0;     dinv[2*t+1] = i1;
    dself[2*t] = i0*i0; dself[2*t+1] = i1*i1;
    fill[2*t] = 0;      fill[2*t+1] = 0;
}

// ================= CSR fill: interleaved (src, nrm) pairs =================
__global__ void k_csr(const int* __restrict__ ei, const float* __restrict__ ew,
                      const float* __restrict__ dinv, const int* __restrict__ rowptr,
                      int* __restrict__ fill, float2* __restrict__ cedge){
    int e = blockIdx.x * 256 + threadIdx.x;
    if (e < N_EDGES){
        int s = ei[e], d = ei[N_EDGES + e];
        int pos = rowptr[d] + atomicAdd(&fill[d], 1);
        float2 v;
        v.x = __int_as_float(s);
        v.y = dinv[s] * ew[e] * dinv[d];
        cedge[pos] = v;
    }
}

// ================= k_gate: 40 edge slots x 8 f4-lanes -> 1 gather round =================
__global__ __launch_bounds__(320) void k_gate(const float* __restrict__ x,
        const float* __restrict__ dself, const int* __restrict__ rowptr,
        const float2* __restrict__ cedge,
        const float* __restrict__ bUV, const float* __restrict__ Wzp, const float* __restrict__ Whp,
        const float* __restrict__ Wred, const float* __restrict__ bred,
        const float* __restrict__ Wi1, const float* __restrict__ bi1, const float* __restrict__ Wc1,
        float* __restrict__ ag, float* __restrict__ bjp, float* __restrict__ hw1){
    int n = blockIdx.x;
    int tid = threadIdx.x;
    __shared__ float part[40*SEQL*IN_F];       // 25.6 KB
    __shared__ float axs[SEQL][IN_F];
    __shared__ float hs[SEQL][HID];
    __shared__ float pw[SEQL][HID];
    __shared__ float hemb[HID];
    const int slot = tid >> 3, fl = tid & 7;   // 40 slots x 8 lanes (float4 each)
    const int f = tid & 63, t = tid >> 6;      // 5 waves for the dense phases
    int beg = rowptr[n], end = rowptr[n+1];
    const float4* X4 = (const float4*)x;
    float4 a0 = {0,0,0,0}, a1 = {0,0,0,0}, a2 = {0,0,0,0}, a3 = {0,0,0,0}, a4 = {0,0,0,0};
    for (int p = beg + slot; p < end; p += 40){
        float2 ed = cedge[p];
        int s = __float_as_int(ed.x); float c = ed.y;
        float4 x0 = X4[(0*N_NODES + s)*8 + fl];
        float4 x1 = X4[(1*N_NODES + s)*8 + fl];
        float4 x2 = X4[(2*N_NODES + s)*8 + fl];
        float4 x3 = X4[(3*N_NODES + s)*8 + fl];
        float4 x4v= X4[(4*N_NODES + s)*8 + fl];
        a0.x += c*x0.x; a0.y += c*x0.y; a0.z += c*x0.z; a0.w += c*x0.w;
        a1.x += c*x1.x; a1.y += c*x1.y; a1.z += c*x1.z; a1.w += c*x1.w;
        a2.x += c*x2.x; a2.y += c*x2.y; a2.z += c*x2.z; a2.w += c*x2.w;
        a3.x += c*x3.x; a3.y += c*x3.y; a3.z += c*x3.z; a3.w += c*x3.w;
        a4.x += c*x4v.x; a4.y += c*x4v.y; a4.z += c*x4v.z; a4.w += c*x4v.w;
    }
    *(float4*)&part[(slot*SEQL + 0)*IN_F + fl*4] = a0;
    *(float4*)&part[(slot*SEQL + 1)*IN_F + fl*4] = a1;
    *(float4*)&part[(slot*SEQL + 2)*IN_F + fl*4] = a2;
    *(float4*)&part[(slot*SEQL + 3)*IN_F + fl*4] = a3;
    *(float4*)&part[(slot*SEQL + 4)*IN_F + fl*4] = a4;
    __syncthreads();
    if (tid < SEQL*IN_F){
        int tt = tid >> 5, ff = tid & 31;
        float s = dself[n] * x[(tt*N_NODES + n)*IN_F + ff];
        #pragma unroll 8
        for (int sl = 0; sl < 40; ++sl) s += part[(sl*SEQL + tt)*IN_F + ff];
        axs[tt][ff] = s;
    }
    __syncthreads();
    {   // 5 waves: gate for timestep t
        float zz = bUV[f], hh = bUV[HID + f];
        #pragma unroll
        for (int i = 0; i < IN_F; ++i){
            float a = axs[t][i];               // wave-uniform LDS broadcast
            zz += a * Wzp[i*HID + f];
            hh += a * Whp[i*HID + f];
        }
        float z = 1.f / (1.f + expf(-zz));
        hs[t][f] = (1.f - z) * tanhf(hh);
    }
    __syncthreads();
    {   float pp = 0.f;
        #pragma unroll
        for (int k = 0; k < HID; ++k) pp += hs[t][k] * Wred[(t*HID + k)*HID + f];
        pw[t][f] = pp;
    }
    __syncthreads();
    if (tid < HID){
        float hr = bred[tid];
        #pragma unroll
        for (int t2 = 0; t2 < SEQL; ++t2) hr += pw[t2][tid];
        hemb[tid] = hr;
    }
    __syncthreads();
    if (t < 3){
        const float* W = (t == 0) ? Wi1 : (t == 1) ? (Wi1 + HID*HID) : Wc1;
        float acc = (t == 1) ? bi1[f] : 0.f;
        #pragma unroll
        for (int k = 0; k < HID; ++k) acc += hemb[k] * W[k*HID + f];
        float* O = (t == 0) ? ag : (t == 1) ? bjp : hw1;
        O[n*HID + f] = acc;                    // bjp has bi1 folded in
    }
}

// ========== k_gcn1s: gcn1 (blocks 0..2047) + scores 128x128 tiles (2048..2303) ==========
// scores depends only on ag/bjp (ready after k_gate) -> overlaps gcn1 on spare CUs.
__global__ __launch_bounds__(512) void k_gcn1s(
        const float* __restrict__ hw1, const float* __restrict__ dself,
        const int* __restrict__ rowptr, const float2* __restrict__ cedge,
        const float* __restrict__ bc1, const float* __restrict__ g1, const float* __restrict__ be1,
        const float* __restrict__ Wc2, float* __restrict__ hw2,
        const float* __restrict__ ag, const float* __restrict__ bjp,
        const float* __restrict__ Wi2, const float* __restrict__ bi2,
        float* __restrict__ outs){
    __shared__ float LP[9280];                 // union: gcn1 2624 f | scores 9280 f (37.1 KB)
    int blk = blockIdx.x;
    int tid = threadIdx.x;
    if (blk < N_NODES){
        float* part = LP;                      // 32*64
        float* hsh  = LP + 2048;               // 64
        float* red8 = LP + 2112;               // 8*64
        int n = blk;
        const int slot = tid >> 4, fl = tid & 15;
        const int f = tid & 63, w = tid >> 6;
        int beg = rowptr[n], end = rowptr[n+1];
        const float4* H4 = (const float4*)hw1;
        float4 acc = {0,0,0,0};
        for (int p = beg + slot; p < end; p += 32){
            float2 ed = cedge[p];
            int s = __float_as_int(ed.x); float c = ed.y;
            float4 h = H4[s*16 + fl];
            acc.x += c*h.x; acc.y += c*h.y; acc.z += c*h.z; acc.w += c*h.w;
        }
        *(float4*)&part[slot*HID + fl*4] = acc;
        __syncthreads();
        if (w == 0){
            float g = bc1[f] + dself[n] * hw1[n*HID + f];
            #pragma unroll 8
            for (int sl = 0; sl < 32; ++sl) g += part[sl*HID + f];
            float sum = g;
            for (int o = 32; o > 0; o >>= 1) sum += __shfl_xor(sum, o, 64);
            float mu = sum * (1.f/64.f);
            float d = g - mu;
            float vs = d * d;
            for (int o = 32; o > 0; o >>= 1) vs += __shfl_xor(vs, o, 64);
            float var = vs * (1.f/64.f);
            float h = d * (1.f / sqrtf(var + LN_EPS)) * g1[f] + be1[f];
            hsh[f] = fmaxf(h, 0.f);
        }
        __syncthreads();
        float s = 0.f;
        #pragma unroll
        for (int k = 0; k < 8; ++k) s += hsh[w*8 + k] * Wc2[(w*8 + k)*HID + f];
        red8[w*HID + f] = s;
        __syncthreads();
        if (w == 0){
            float o = 0.f;
            #pragma unroll
            for (int k = 0; k < 8; ++k) o += red8[k*HID + f];
            hw2[n*HID + f] = o;
        }
    } else {
        float* as = LP;                        // 128*36
        float* bs = LP + 4608;                 // 128*36
        float* wv = LP + 9216;                 // 64
        int tl = blk - N_NODES;                // 0..255
        int i0 = (tl >> 4) * 128;
        int j0 = (tl & 15) * 128;
        const float4* A4 = (const float4*)ag;
        const float4* B4 = (const float4*)bjp;
        if (tid < 64) wv[tid] = Wi2[tid];
        const int tj = tid & 15;               // cols {tj + 16m}
        const int rg = tid >> 4;               // rows {rg + 32k}
        float acc[4][8];
        #pragma unroll
        for (int k = 0; k < 4; ++k)
            #pragma unroll
            for (int m = 0; m < 8; ++m) acc[k][m] = 0.f;
        #pragma unroll
        for (int half = 0; half < 2; ++half){
            __syncthreads();
            #pragma unroll
            for (int k = 0; k < 2; ++k){
                int idx = tid + k*512;         // 1024 = 128 rows x 8 f4-chunks
                int r = idx >> 3, c = idx & 7;
                *(float4*)&as[r*36 + c*4] = A4[(i0 + r)*16 + half*8 + c];
                *(float4*)&bs[r*36 + c*4] = B4[(j0 + r)*16 + half*8 + c];
            }
            __syncthreads();
            #pragma unroll
            for (int fc = 0; fc < 8; ++fc){
                float4 w4 = *(float4*)&wv[half*32 + fc*4];
                float4 bv[8];
                #pragma unroll
                for (int m = 0; m < 8; ++m) bv[m] = *(float4*)&bs[(tj + 16*m)*36 + fc*4];
                #pragma unroll
                for (int k = 0; k < 4; ++k){
                    float4 av = *(float4*)&as[(rg + 32*k)*36 + fc*4];
                    #pragma unroll
                    for (int m = 0; m < 8; ++m){
                        acc[k][m] = fmaf(fmaxf(av.x + bv[m].x, 0.f), w4.x, acc[k][m]);
                        acc[k][m] = fmaf(fmaxf(av.y + bv[m].y, 0.f), w4.y, acc[k][m]);
                        acc[k][m] = fmaf(fmaxf(av.z + bv[m].z, 0.f), w4.z, acc[k][m]);
                        acc[k][m] = fmaf(fmaxf(av.w + bv[m].w, 0.f), w4.w, acc[k][m]);
                    }
                }
            }
        }
        float bi2v = bi2[0];
        #pragma unroll
        for (int k = 0; k < 4; ++k){
            #pragma unroll
            for (int m = 0; m < 8; ++m){
                long ro = (long)(i0 + rg + 32*k) * N_NODES + j0 + tj + 16*m;
                outs[ro] = acc[k][m] + bi2v;
            }
        }
    }
}

// ================= gcn2: 32 slots x 16 f4-lanes, LN+relu, node_pred out =================
__global__ __launch_bounds__(512) void k_gcn2(
        const float* __restrict__ hw2, const float* __restrict__ dself,
        const int* __restrict__ rowptr, const float2* __restrict__ cedge,
        const float* __restrict__ bc2, const float* __restrict__ g2, const float* __restrict__ be2,
        const float* __restrict__ Wout, const float* __restrict__ bout, float* __restrict__ outp){
    int n = blockIdx.x;
    int tid = threadIdx.x;
    __shared__ float part[32*HID];
    __shared__ float hsh[HID];
    const int slot = tid >> 4, fl = tid & 15;
    const int f = tid & 63, w = tid >> 6;
    int beg = rowptr[n], end = rowptr[n+1];
    const float4* H4 = (const float4*)hw2;
    float4 acc = {0,0,0,0};
    for (int p = beg + slot; p < end; p += 32){
        float2 ed = cedge[p];
        int s = __float_as_int(ed.x); float c = ed.y;
        float4 h = H4[s*16 + fl];
        acc.x += c*h.x; acc.y += c*h.y; acc.z += c*h.z; acc.w += c*h.w;
    }
    *(float4*)&part[slot*HID + fl*4] = acc;
    __syncthreads();
    if (w == 0){
        float g = bc2[f] + dself[n] * hw2[n*HID + f];
        #pragma unroll 8
        for (int sl = 0; sl < 32; ++sl) g += part[sl*HID + f];
        float sum = g;
        for (int o = 32; o > 0; o >>= 1) sum += __shfl_xor(sum, o, 64);
        float mu = sum * (1.f/64.f);
        float d = g - mu;
        float vs = d * d;
        for (int o = 32; o > 0; o >>= 1) vs += __shfl_xor(vs, o, 64);
        float var = vs * (1.f/64.f);
        float h = d * (1.f / sqrtf(var + LN_EPS)) * g2[f] + be2[f];
        hsh[f] = fmaxf(h, 0.f);
    }
    __syncthreads();
    if (w == 0 && f < OUT_F){
        float s = bout[f];
        #pragma unroll
        for (int k = 0; k < HID; ++k) s += hsh[k] * Wout[k*OUT_F + f];
        outp[n*OUT_F + f] = s;
    }
}

extern "C" void kernel_launch(void* const* d_in, const int* in_sizes, int n_in,
                              void* d_out, int out_size, void* d_ws, size_t ws_size,
                              hipStream_t stream){
    const float* x   = (const float*)d_in[0];
    const float* ew  = (const float*)d_in[1];
    const float* Wcz = (const float*)d_in[2];  const float* bcz = (const float*)d_in[3];
    const float* Wlz = (const float*)d_in[4];  const float* blz = (const float*)d_in[5];
    // d_in[6..9]: Wcr/bcr/Wlr/blr — dead code (H=0 so reset gate has no effect)
    const float* Wch = (const float*)d_in[10]; const float* bch = (const float*)d_in[11];
    const float* Wlh = (const float*)d_in[12]; const float* blh = (const float*)d_in[13];
    const float* Wred= (const float*)d_in[14]; const float* bred= (const float*)d_in[15];
    const float* Wc1 = (const float*)d_in[16]; const float* bc1 = (const float*)d_in[17];
    const float* Wc2 = (const float*)d_in[18]; const float* bc2 = (const float*)d_in[19];
    const float* g1  = (const float*)d_in[20]; const float* be1 = (const float*)d_in[21];
    const float* g2  = (const float*)d_in[22]; const float* be2 = (const float*)d_in[23];
    const float* Wout= (const float*)d_in[24]; const float* bout= (const float*)d_in[25];
    const float* Wi1 = (const float*)d_in[26]; const float* bi1 = (const float*)d_in[27];
    const float* Wi2 = (const float*)d_in[28]; const float* bi2 = (const float*)d_in[29];
    const int*  ei  = (const int*)d_in[30];

    float* w = (float*)d_ws;            // float offsets, 16B aligned
    float* deg    = w;                  // 2048   [memset 16 KB covers deg+cnt]
    int*   cnt    = (int*)(w + 2048);   // 2048
    int*   rowptr = (int*)(w + 4096);   // 2049 (pad 2560)
    float* dinv   = w + 6656;           // 2048
    float* dself  = w + 8704;           // 2048
    int*   fill   = (int*)(w + 10752);  // 2048
    float2* cedge = (float2*)(w + 12800); // 65536 pairs = 131072 floats
    float* Wzp    = w + 143872;         // 2048
    float* Whp    = w + 145920;         // 2048
    float* bUV    = w + 147968;         // 128
    float* ag     = w + 148096;         // 131072
    float* bjp    = w + 279168;         // 131072
    float* hw1    = w + 410240;         // 131072
    float* hw2    = w + 541312;         // 131072

    hipMemsetAsync(deg, 0, 16384, stream);
    k_deg_wcomb<<<258, 256, 0, stream>>>(ei, ew, Wcz, Wlz, bcz, blz, Wch, Wlh, bch, blh,
                                         deg, cnt, Wzp, Whp, bUV);
    k_scan<<<1, 1024, 0, stream>>>(deg, cnt, rowptr, dinv, dself, fill);
    k_csr<<<N_EDGES/256, 256, 0, stream>>>(ei, ew, dinv, rowptr, fill, cedge);
    k_gate<<<N_NODES, 320, 0, stream>>>(x, dself, rowptr, cedge, bUV, Wzp, Whp,
                                        Wred, bred, Wi1, bi1, Wc1, ag, bjp, hw1);
    k_gcn1s<<<N_NODES + 256, 512, 0, stream>>>(hw1, dself, rowptr, cedge, bc1, g1, be1, Wc2, hw2,
                                               ag, bjp, Wi2, bi2,
                                               (float*)d_out + N_NODES*OUT_F);
    k_gcn2<<<N_NODES, 512, 0, stream>>>(hw2, dself, rowptr, cedge, bc2, g2, be2, Wout, bout,
                                        (float*)d_out);
}

// Round 13
// 218.031 us; speedup vs baseline: 1.0611x; 1.0611x over previous
//
#include <hip/hip_runtime.h>
#include <math.h>

#define N_NODES 2048
#define N_EDGES 65536
#define SEQL 5
#define IN_F 32
#define HID 64
#define OUT_F 16
#define LN_EPS 1e-5f

// ================= k_deg_wcomb: 258 blocks x 256 =================
__global__ __launch_bounds__(256) void k_deg_wcomb(
        const int* __restrict__ ei, const float* __restrict__ ew,
        const float* __restrict__ Wcz, const float* __restrict__ Wlz,
        const float* __restrict__ bcz, const float* __restrict__ blz,
        const float* __restrict__ Wch, const float* __restrict__ Wlh,
        const float* __restrict__ bch, const float* __restrict__ blh,
        float* __restrict__ deg, int* __restrict__ cnt,
        float* __restrict__ Wzp, float* __restrict__ Whp, float* __restrict__ bUV){
    int b = blockIdx.x, t = threadIdx.x;
    if (b < 256){
        int e = b * 256 + t;
        int d = ei[N_EDGES + e];
        atomicAdd(&deg[d], ew[e]);
        atomicAdd(&cnt[d], 1);
    } else {
        const float* Wc = (b == 256) ? Wcz : Wch;
        const float* Wl = (b == 256) ? Wlz : Wlh;
        const float* bc = (b == 256) ? bcz : bch;
        const float* bl = (b == 256) ? blz : blh;
        float* Wp = (b == 256) ? Wzp : Whp;
        for (int idx = t; idx < IN_F*HID; idx += 256){
            int i = idx >> 6, f = idx & 63;
            float s = 0.f;
            #pragma unroll 8
            for (int k = 0; k < HID; ++k) s += Wc[i*HID+k] * Wl[k*HID+f];
            Wp[idx] = s;
        }
        if (t < HID){
            float s = bl[t];
            for (int k = 0; k < HID; ++k) s += bc[k] * Wl[k*HID+t];
            bUV[(b-256)*HID + t] = s;
        }
    }
}

// ================= k_scan: 1 block x 1024 =================
__global__ __launch_bounds__(1024) void k_scan(
        const float* __restrict__ deg, const int* __restrict__ cnt,
        int* __restrict__ rowptr, float* __restrict__ dinv, float* __restrict__ dself,
        int* __restrict__ fill){
    __shared__ int sc[1024];
    int t = threadIdx.x;
    int c0 = cnt[2*t], c1 = cnt[2*t+1];
    int ts = c0 + c1;
    sc[t] = ts;
    __syncthreads();
    for (int off = 1; off < 1024; off <<= 1){
        int v = (t >= off) ? sc[t - off] : 0;
        __syncthreads();
        sc[t] += v;
        __syncthreads();
    }
    int exc = sc[t] - ts;
    rowptr[2*t]   = exc;
    rowptr[2*t+1] = exc + c0;
    if (t == 1023) rowptr[N_NODES] = sc[t];
    float i0 = 1.f / sqrtf(deg[2*t] + 1.f);
    float i1 = 1.f / sqrtf(deg[2*t+1] + 1.f);
    dinv[2*t] = i0;     dinv[2*t+1] = i1;
    dself[2*t] = i0*i0; dself[2*t+1] = i1*i1;
    fill[2*t] = 0;      fill[2*t+1] = 0;
}

// ================= CSR fill: interleaved (src, nrm) pairs =================
__global__ void k_csr(const int* __restrict__ ei, const float* __restrict__ ew,
                      const float* __restrict__ dinv, const int* __restrict__ rowptr,
                      int* __restrict__ fill, float2* __restrict__ cedge){
    int e = blockIdx.x * 256 + threadIdx.x;
    if (e < N_EDGES){
        int s = ei[e], d = ei[N_EDGES + e];
        int pos = rowptr[d] + atomicAdd(&fill[d], 1);
        float2 v;
        v.x = __int_as_float(s);
        v.y = dinv[s] * ew[e] * dinv[d];
        cedge[pos] = v;
    }
}

// ================= k_gate: 40 edge slots x 8 f4-lanes -> 1 gather round =================
__global__ __launch_bounds__(320) void k_gate(const float* __restrict__ x,
        const float* __restrict__ dself, const int* __restrict__ rowptr,
        const float2* __restrict__ cedge,
        const float* __restrict__ bUV, const float* __restrict__ Wzp, const float* __restrict__ Whp,
        const float* __restrict__ Wred, const float* __restrict__ bred,
        const float* __restrict__ Wi1, const float* __restrict__ bi1, const float* __restrict__ Wc1,
        float* __restrict__ ag, float* __restrict__ bjp, float* __restrict__ hw1){
    int n = blockIdx.x;
    int tid = threadIdx.x;
    __shared__ float part[40*SEQL*IN_F];       // 25.6 KB
    __shared__ float axs[SEQL][IN_F];
    __shared__ float hs[SEQL][HID];
    __shared__ float pw[SEQL][HID];
    __shared__ float hemb[HID];
    const int slot = tid >> 3, fl = tid & 7;   // 40 slots x 8 lanes (float4 each)
    const int f = tid & 63, t = tid >> 6;      // 5 waves for the dense phases
    int beg = rowptr[n], end = rowptr[n+1];
    const float4* X4 = (const float4*)x;
    float4 a0 = {0,0,0,0}, a1 = {0,0,0,0}, a2 = {0,0,0,0}, a3 = {0,0,0,0}, a4 = {0,0,0,0};
    for (int p = beg + slot; p < end; p += 40){
        float2 ed = cedge[p];
        int s = __float_as_int(ed.x); float c = ed.y;
        float4 x0 = X4[(0*N_NODES + s)*8 + fl];
        float4 x1 = X4[(1*N_NODES + s)*8 + fl];
        float4 x2 = X4[(2*N_NODES + s)*8 + fl];
        float4 x3 = X4[(3*N_NODES + s)*8 + fl];
        float4 x4v= X4[(4*N_NODES + s)*8 + fl];
        a0.x += c*x0.x; a0.y += c*x0.y; a0.z += c*x0.z; a0.w += c*x0.w;
        a1.x += c*x1.x; a1.y += c*x1.y; a1.z += c*x1.z; a1.w += c*x1.w;
        a2.x += c*x2.x; a2.y += c*x2.y; a2.z += c*x2.z; a2.w += c*x2.w;
        a3.x += c*x3.x; a3.y += c*x3.y; a3.z += c*x3.z; a3.w += c*x3.w;
        a4.x += c*x4v.x; a4.y += c*x4v.y; a4.z += c*x4v.z; a4.w += c*x4v.w;
    }
    *(float4*)&part[(slot*SEQL + 0)*IN_F + fl*4] = a0;
    *(float4*)&part[(slot*SEQL + 1)*IN_F + fl*4] = a1;
    *(float4*)&part[(slot*SEQL + 2)*IN_F + fl*4] = a2;
    *(float4*)&part[(slot*SEQL + 3)*IN_F + fl*4] = a3;
    *(float4*)&part[(slot*SEQL + 4)*IN_F + fl*4] = a4;
    __syncthreads();
    if (tid < SEQL*IN_F){
        int tt = tid >> 5, ff = tid & 31;
        float s = dself[n] * x[(tt*N_NODES + n)*IN_F + ff];
        #pragma unroll 8
        for (int sl = 0; sl < 40; ++sl) s += part[(sl*SEQL + tt)*IN_F + ff];
        axs[tt][ff] = s;
    }
    __syncthreads();
    {   // 5 waves: gate for timestep t
        float zz = bUV[f], hh = bUV[HID + f];
        #pragma unroll
        for (int i = 0; i < IN_F; ++i){
            float a = axs[t][i];               // wave-uniform LDS broadcast
            zz += a * Wzp[i*HID + f];
            hh += a * Whp[i*HID + f];
        }
        float z = 1.f / (1.f + expf(-zz));
        hs[t][f] = (1.f - z) * tanhf(hh);
    }
    __syncthreads();
    {   float pp = 0.f;
        #pragma unroll
        for (int k = 0; k < HID; ++k) pp += hs[t][k] * Wred[(t*HID + k)*HID + f];
        pw[t][f] = pp;
    }
    __syncthreads();
    if (tid < HID){
        float hr = bred[tid];
        #pragma unroll
        for (int t2 = 0; t2 < SEQL; ++t2) hr += pw[t2][tid];
        hemb[tid] = hr;
    }
    __syncthreads();
    if (t < 3){
        const float* W = (t == 0) ? Wi1 : (t == 1) ? (Wi1 + HID*HID) : Wc1;
        float acc = (t == 1) ? bi1[f] : 0.f;
        #pragma unroll
        for (int k = 0; k < HID; ++k) acc += hemb[k] * W[k*HID + f];
        float* O = (t == 0) ? ag : (t == 1) ? bjp : hw1;
        O[n*HID + f] = acc;                    // bjp has bi1 folded in
    }
}

// ================= gcn1: 32 slots x 16 f4-lanes, LN+relu, premultiply Wc2 =================
__global__ __launch_bounds__(512) void k_gcn1(
        const float* __restrict__ hw1, const float* __restrict__ dself,
        const int* __restrict__ rowptr, const float2* __restrict__ cedge,
        const float* __restrict__ bc1, const float* __restrict__ g1, const float* __restrict__ be1,
        const float* __restrict__ Wc2, float* __restrict__ hw2){
    int n = blockIdx.x;
    int tid = threadIdx.x;
    __shared__ float part[32*HID];             // 8 KB
    __shared__ float hsh[HID];
    __shared__ float red8[8*HID];
    const int slot = tid >> 4, fl = tid & 15;
    const int f = tid & 63, w = tid >> 6;
    int beg = rowptr[n], end = rowptr[n+1];
    const float4* H4 = (const float4*)hw1;
    float4 acc = {0,0,0,0};
    for (int p = beg + slot; p < end; p += 32){
        float2 ed = cedge[p];
        int s = __float_as_int(ed.x); float c = ed.y;
        float4 h = H4[s*16 + fl];
        acc.x += c*h.x; acc.y += c*h.y; acc.z += c*h.z; acc.w += c*h.w;
    }
    *(float4*)&part[slot*HID + fl*4] = acc;
    __syncthreads();
    if (w == 0){
        float g = bc1[f] + dself[n] * hw1[n*HID + f];
        #pragma unroll 8
        for (int sl = 0; sl < 32; ++sl) g += part[sl*HID + f];
        float sum = g;
        for (int o = 32; o > 0; o >>= 1) sum += __shfl_xor(sum, o, 64);
        float mu = sum * (1.f/64.f);
        float d = g - mu;
        float vs = d * d;
        for (int o = 32; o > 0; o >>= 1) vs += __shfl_xor(vs, o, 64);
        float var = vs * (1.f/64.f);
        float h = d * (1.f / sqrtf(var + LN_EPS)) * g1[f] + be1[f];
        hsh[f] = fmaxf(h, 0.f);
    }
    __syncthreads();
    float s = 0.f;
    #pragma unroll
    for (int k = 0; k < 8; ++k) s += hsh[w*8 + k] * Wc2[(w*8 + k)*HID + f];
    red8[w*HID + f] = s;
    __syncthreads();
    if (w == 0){
        float o = 0.f;
        #pragma unroll
        for (int k = 0; k < 8; ++k) o += red8[k*HID + f];
        hw2[n*HID + f] = o;
    }
}

// ================= gcn2: 32 slots x 16 f4-lanes, LN+relu, node_pred out =================
__global__ __launch_bounds__(512) void k_gcn2(
        const float* __restrict__ hw2, const float* __restrict__ dself,
        const int* __restrict__ rowptr, const float2* __restrict__ cedge,
        const float* __restrict__ bc2, const float* __restrict__ g2, const float* __restrict__ be2,
        const float* __restrict__ Wout, const float* __restrict__ bout, float* __restrict__ outp){
    int n = blockIdx.x;
    int tid = threadIdx.x;
    __shared__ float part[32*HID];
    __shared__ float hsh[HID];
    const int slot = tid >> 4, fl = tid & 15;
    const int f = tid & 63, w = tid >> 6;
    int beg = rowptr[n], end = rowptr[n+1];
    const float4* H4 = (const float4*)hw2;
    float4 acc = {0,0,0,0};
    for (int p = beg + slot; p < end; p += 32){
        float2 ed = cedge[p];
        int s = __float_as_int(ed.x); float c = ed.y;
        float4 h = H4[s*16 + fl];
        acc.x += c*h.x; acc.y += c*h.y; acc.z += c*h.z; acc.w += c*h.w;
    }
    *(float4*)&part[slot*HID + fl*4] = acc;
    __syncthreads();
    if (w == 0){
        float g = bc2[f] + dself[n] * hw2[n*HID + f];
        #pragma unroll 8
        for (int sl = 0; sl < 32; ++sl) g += part[sl*HID + f];
        float sum = g;
        for (int o = 32; o > 0; o >>= 1) sum += __shfl_xor(sum, o, 64);
        float mu = sum * (1.f/64.f);
        float d = g - mu;
        float vs = d * d;
        for (int o = 32; o > 0; o >>= 1) vs += __shfl_xor(vs, o, 64);
        float var = vs * (1.f/64.f);
        float h = d * (1.f / sqrtf(var + LN_EPS)) * g2[f] + be2[f];
        hsh[f] = fmaxf(h, 0.f);
    }
    __syncthreads();
    if (w == 0 && f < OUT_F){
        float s = bout[f];
        #pragma unroll
        for (int k = 0; k < HID; ++k) s += hsh[k] * Wout[k*OUT_F + f];
        outp[n*OUT_F + f] = s;
    }
}

// ================= k_scores: 128x128 tile, 4i x 8j regs, b128 LDS, f in 2 halves =================
__global__ __launch_bounds__(512) void k_scores(const float* __restrict__ ag, const float* __restrict__ bjp,
        const float* __restrict__ Wi2, const float* __restrict__ bi2, float* __restrict__ outs){
    __shared__ float as[128*36];   // [row][f-half], stride 36 (9 f4-groups: odd -> 2-way free)
    __shared__ float bs[128*36];
    __shared__ float wv[64];
    int tid = threadIdx.x;
    int i0 = (blockIdx.x >> 4) * 128;
    int j0 = (blockIdx.x & 15) * 128;
    const float4* A4 = (const float4*)ag;
    const float4* B4 = (const float4*)bjp;
    if (tid < 64) wv[tid] = Wi2[tid];
    const int tj = tid & 15;        // cols {tj + 16m}, m=0..7
    const int rg = tid >> 4;        // rows {rg + 32k}, k=0..3
    float acc[4][8];
    #pragma unroll
    for (int k = 0; k < 4; ++k)
        #pragma unroll
        for (int m = 0; m < 8; ++m) acc[k][m] = 0.f;
    #pragma unroll
    for (int half = 0; half < 2; ++half){
        __syncthreads();
        #pragma unroll
        for (int k = 0; k < 2; ++k){
            int idx = tid + k*512;            // 1024 = 128 rows x 8 f4-chunks
            int r = idx >> 3, c = idx & 7;
            *(float4*)&as[r*36 + c*4] = A4[(i0 + r)*16 + half*8 + c];
            *(float4*)&bs[r*36 + c*4] = B4[(j0 + r)*16 + half*8 + c];
        }
        __syncthreads();
        #pragma unroll
        for (int fc = 0; fc < 8; ++fc){
            float4 w4 = *(float4*)&wv[half*32 + fc*4];
            float4 bv[8];
            #pragma unroll
            for (int m = 0; m < 8; ++m) bv[m] = *(float4*)&bs[(tj + 16*m)*36 + fc*4];
            #pragma unroll
            for (int k = 0; k < 4; ++k){
                float4 av = *(float4*)&as[(rg + 32*k)*36 + fc*4];
                #pragma unroll
                for (int m = 0; m < 8; ++m){
                    acc[k][m] = fmaf(fmaxf(av.x + bv[m].x, 0.f), w4.x, acc[k][m]);
                    acc[k][m] = fmaf(fmaxf(av.y + bv[m].y, 0.f), w4.y, acc[k][m]);
                    acc[k][m] = fmaf(fmaxf(av.z + bv[m].z, 0.f), w4.z, acc[k][m]);
                    acc[k][m] = fmaf(fmaxf(av.w + bv[m].w, 0.f), w4.w, acc[k][m]);
                }
            }
        }
    }
    float bi2v = bi2[0];
    #pragma unroll
    for (int k = 0; k < 4; ++k){
        #pragma unroll
        for (int m = 0; m < 8; ++m){
            long ro = (long)(i0 + rg + 32*k) * N_NODES + j0 + tj + 16*m;
            outs[ro] = acc[k][m] + bi2v;
        }
    }
}

extern "C" void kernel_launch(void* const* d_in, const int* in_sizes, int n_in,
                              void* d_out, int out_size, void* d_ws, size_t ws_size,
                              hipStream_t stream){
    const float* x   = (const float*)d_in[0];
    const float* ew  = (const float*)d_in[1];
    const float* Wcz = (const float*)d_in[2];  const float* bcz = (const float*)d_in[3];
    const float* Wlz = (const float*)d_in[4];  const float* blz = (const float*)d_in[5];
    // d_in[6..9]: Wcr/bcr/Wlr/blr — dead code (H=0 so reset gate has no effect)
    const float* Wch = (const float*)d_in[10]; const float* bch = (const float*)d_in[11];
    const float* Wlh = (const float*)d_in[12]; const float* blh = (const float*)d_in[13];
    const float* Wred= (const float*)d_in[14]; const float* bred= (const float*)d_in[15];
    const float* Wc1 = (const float*)d_in[16]; const float* bc1 = (const float*)d_in[17];
    const float* Wc2 = (const float*)d_in[18]; const float* bc2 = (const float*)d_in[19];
    const float* g1  = (const float*)d_in[20]; const float* be1 = (const float*)d_in[21];
    const float* g2  = (const float*)d_in[22]; const float* be2 = (const float*)d_in[23];
    const float* Wout= (const float*)d_in[24]; const float* bout= (const float*)d_in[25];
    const float* Wi1 = (const float*)d_in[26]; const float* bi1 = (const float*)d_in[27];
    const float* Wi2 = (const float*)d_in[28]; const float* bi2 = (const float*)d_in[29];
    const int*  ei  = (const int*)d_in[30];

    float* w = (float*)d_ws;            // float offsets, 16B aligned
    float* deg    = w;                  // 2048   [memset 16 KB covers deg+cnt]
    int*   cnt    = (int*)(w + 2048);   // 2048
    int*   rowptr = (int*)(w + 4096);   // 2049 (pad 2560)
    float* dinv   = w + 6656;           // 2048
    float* dself  = w + 8704;           // 2048
    int*   fill   = (int*)(w + 10752);  // 2048
    float2* cedge = (float2*)(w + 12800); // 65536 pairs = 131072 floats
    float* Wzp    = w + 143872;         // 2048
    float* Whp    = w + 145920;         // 2048
    float* bUV    = w + 147968;         // 128
    float* ag     = w + 148096;         // 131072
    float* bjp    = w + 279168;         // 131072
    float* hw1    = w + 410240;         // 131072
    float* hw2    = w + 541312;         // 131072

    hipMemsetAsync(deg, 0, 16384, stream);
    k_deg_wcomb<<<258, 256, 0, stream>>>(ei, ew, Wcz, Wlz, bcz, blz, Wch, Wlh, bch, blh,
                                         deg, cnt, Wzp, Whp, bUV);
    k_scan<<<1, 1024, 0, stream>>>(deg, cnt, rowptr, dinv, dself, fill);
    k_csr<<<N_EDGES/256, 256, 0, stream>>>(ei, ew, dinv, rowptr, fill, cedge);
    k_gate<<<N_NODES, 320, 0, stream>>>(x, dself, rowptr, cedge, bUV, Wzp, Whp,
                                        Wred, bred, Wi1, bi1, Wc1, ag, bjp, hw1);
    k_gcn1<<<N_NODES, 512, 0, stream>>>(hw1, dself, rowptr, cedge, bc1, g1, be1, Wc2, hw2);
    k_gcn2<<<N_NODES, 512, 0, stream>>>(hw2, dself, rowptr, cedge, bc2, g2, be2, Wout, bout,
                                        (float*)d_out);
    k_scores<<<256, 512, 0, stream>>>(ag, bjp, Wi2, bi2, (float*)d_out + N_NODES*OUT_F);
}